// Round 6
// baseline (19500.069 us; speedup 1.0000x reference)
//
#include <hip/hip_runtime.h>

typedef unsigned short u16;
typedef _Float16 f16_t;
typedef f16_t f16x8 __attribute__((ext_vector_type(8)));
typedef float f32x4 __attribute__((ext_vector_type(4)));

#define T_STEPS 256
#define IN_DIM  5
#define ROWS    16      // batch rows per block
#define NBLK    256     // 256 * 16 = B = 4096

// d_ws layout (u16 elements):
//   ws0: [64 nt][9 ks][64 lane][8 e] = 294912   (w_hh0, ks=8 appends w_ih0 zero-padded)
//   ws1: [64 nt][8 ks][64 lane][8 e] = 262144   @ 294912   (w_ih1)
//   ws2: [64 nt][8 ks][64 lane][8 e] = 262144   @ 557056   (w_hh1)
//   biases (float) @ byte 1638400: bias0[1024]=b_ih0+b_hh0, bias1[1024]=b_ih1+b_hh1

__device__ __forceinline__ float sigf(float x)  { return 1.0f / (1.0f + __expf(-x)); }
__device__ __forceinline__ float tanh_f(float x){ return 1.0f - 2.0f / (__expf(2.0f * x) + 1.0f); }

// LDS-visibility barrier, lgkm-only (no vmem drain). Proven in rounds 3/5:
// memory clobbers on BOTH sides of s_barrier + sched_barrier(0) so no LDS
// access can be hoisted across the rendezvous at IR or MIR level.
#define BARRIER() do { \
    asm volatile("s_waitcnt lgkmcnt(0)" ::: "memory"); \
    __builtin_amdgcn_s_barrier(); \
    asm volatile("" ::: "memory"); \
    __builtin_amdgcn_sched_barrier(0); \
} while (0)

__global__ void prep_kernel(const float* __restrict__ wih0, const float* __restrict__ whh0,
                            const float* __restrict__ wih1, const float* __restrict__ whh1,
                            const float* __restrict__ bih0, const float* __restrict__ bhh0,
                            const float* __restrict__ bih1, const float* __restrict__ bhh1,
                            u16* __restrict__ wsw, float* __restrict__ biases)
{
    int j = blockIdx.x * blockDim.x + threadIdx.x;
    if (j < 36864) {                              // ws0
        int nt = j / (9 * 64); int rem = j - nt * 9 * 64;
        int ks = rem >> 6; int lane = rem & 63;
        int n = nt * 16 + (lane & 15);
        u16 tmp[8];
#pragma unroll
        for (int e = 0; e < 8; ++e) {
            int kloc = ((lane >> 4) << 3) + e;
            float v;
            if (ks < 8) v = whh0[n * 256 + ks * 32 + kloc];
            else        v = (kloc < IN_DIM) ? wih0[n * IN_DIM + kloc] : 0.0f;
            tmp[e] = __builtin_bit_cast(u16, (f16_t)v);
        }
        *(uint4*)(wsw + (size_t)j * 8) = *(uint4*)tmp;
    } else if (j < 69632) {                       // ws1
        int q = j - 36864;
        int nt = q / (8 * 64); int rem = q - nt * 8 * 64;
        int ks = rem >> 6; int lane = rem & 63;
        int n = nt * 16 + (lane & 15);
        u16 tmp[8];
#pragma unroll
        for (int e = 0; e < 8; ++e) {
            int kloc = ((lane >> 4) << 3) + e;
            float v = wih1[n * 256 + ks * 32 + kloc];
            tmp[e] = __builtin_bit_cast(u16, (f16_t)v);
        }
        *(uint4*)(wsw + 294912 + (size_t)q * 8) = *(uint4*)tmp;
    } else if (j < 102400) {                      // ws2
        int q = j - 69632;
        int nt = q / (8 * 64); int rem = q - nt * 8 * 64;
        int ks = rem >> 6; int lane = rem & 63;
        int n = nt * 16 + (lane & 15);
        u16 tmp[8];
#pragma unroll
        for (int e = 0; e < 8; ++e) {
            int kloc = ((lane >> 4) << 3) + e;
            float v = whh1[n * 256 + ks * 32 + kloc];
            tmp[e] = __builtin_bit_cast(u16, (f16_t)v);
        }
        *(uint4*)(wsw + 557056 + (size_t)q * 8) = *(uint4*)tmp;
    } else if (j < 103424) {                      // bias0
        int i = j - 102400;
        biases[i] = bih0[i] + bhh0[i];
    } else if (j < 104448) {                      // bias1
        int i = j - 103424;
        biases[1024 + i] = bih1[i] + bhh1[i];
    }
}

__global__ __launch_bounds__(1024, 4) void lstm_fused(
    const float* __restrict__ x, const u16* __restrict__ wsw,
    const float* __restrict__ biases, const float* __restrict__ fcw_g,
    const float* __restrict__ fcb_g, float* __restrict__ out)
{
    __shared__ u16 h0b[2 * ROWS * 256];   // fp16 bits, row stride 512B, XOR-swizzled
    __shared__ u16 h1b[2 * ROWS * 256];
    __shared__ u16 xbb[2 * ROWS * 32];    // x_t staged, zero-padded

    const int tid  = threadIdx.x;
    const int wv   = tid >> 6;         // wave 0..15: owns hidden cols [16wv, 16wv+16)
    const int lane = tid & 63;
    const int lrow = lane & 15;
    const int lkg  = lane >> 4;
    const int r0   = blockIdx.x * ROWS;

    const u16* ws0 = wsw;
    const u16* ws1 = wsw + 294912;
    const u16* ws2 = wsw + 557056;
    const float* bias0 = biases;
    const float* bias1 = biases + 1024;

    int o0[4], o12[4];
#pragma unroll
    for (int g = 0; g < 4; ++g) {
        int nt = g * 16 + wv;
        o0[g]  = nt * 9 * 512 + lane * 8;
        o12[g] = nt * 8 * 512 + lane * 8;
    }

    // ---- resident weights: 100 f16x8 fragments, laundered into AGPRs.
    // The volatile "+a" asm (a) forces the values into the accumulator side
    // of the gfx950 unified register file (MFMA reads A/B from AGPR natively)
    // and (b) makes rematerialization of the loads ILLEGAL — the values are
    // volatile-asm results, not load results. This is the fix for round 4's
    // silent respill-to-global (VGPR_Count=64, FETCH 45.7 GB).
    f16x8 w0[9][4], w1[8][4], w2[8][4];
#pragma unroll
    for (int ks = 0; ks < 9; ++ks)
#pragma unroll
        for (int g = 0; g < 4; ++g)
            w0[ks][g] = *(const f16x8*)(ws0 + o0[g] + ks * 512);
#pragma unroll
    for (int ks = 0; ks < 8; ++ks)
#pragma unroll
        for (int g = 0; g < 4; ++g) {
            w1[ks][g] = *(const f16x8*)(ws1 + o12[g] + ks * 512);
            w2[ks][g] = *(const f16x8*)(ws2 + o12[g] + ks * 512);
        }
#pragma unroll
    for (int ks = 0; ks < 9; ++ks)
#pragma unroll
        for (int g = 0; g < 4; ++g)
            asm volatile("" : "+a"(w0[ks][g]));
#pragma unroll
    for (int ks = 0; ks < 8; ++ks)
#pragma unroll
        for (int g = 0; g < 4; ++g) {
            asm volatile("" : "+a"(w1[ks][g]));
            asm volatile("" : "+a"(w2[ks][g]));
        }

    float bi0[4], bi1[4];
#pragma unroll
    for (int g = 0; g < 4; ++g) {
        bi0[g] = bias0[g * 256 + wv * 16 + lrow];
        bi1[g] = bias1[g * 256 + wv * 16 + lrow];
    }
    float fcw[4];
#pragma unroll
    for (int r = 0; r < 4; ++r) fcw[r] = fcw_g[lane * 4 + r];
    const float fcb = fcb_g[0];

    // zero LDS state + both xb buffers
    for (int i = tid; i < 2 * ROWS * 256; i += 1024) { h0b[i] = 0; h1b[i] = 0; }
    xbb[tid] = 0;                      // 1024 threads cover all 1024 xb entries
    __syncthreads();
    // stage x_0 into xb buffer 0
    const int xrow = tid / IN_DIM, xk = tid - (tid / IN_DIM) * IN_DIM;
    if (tid < ROWS * IN_DIM) {
        float v = x[((size_t)(r0 + xrow) * T_STEPS + 0) * IN_DIM + xk];
        int byteo = xrow * 64 + ((2 * xk) ^ ((xrow & 3) << 4));
        *(u16*)((char*)xbb + byteo) = __builtin_bit_cast(u16, (f16_t)v);
    }

    float c0[4] = {0.f, 0.f, 0.f, 0.f};
    float c1[4] = {0.f, 0.f, 0.f, 0.f};

    __syncthreads();

    const int aswz = (lrow & 7) << 4;
    const int xswz = (lrow & 3) << 4;

#pragma unroll 1
    for (int t = 0; t < T_STEPS; ++t) {
        const int p = t & 1;
        const u16* h0p = h0b + p * (ROWS * 256);
        const u16* h1p = h1b + p * (ROWS * 256);
        u16* h0w = h0b + (p ^ 1) * (ROWS * 256);
        u16* h1w = h1b + (p ^ 1) * (ROWS * 256);
        const u16* xbp = xbb + p * (ROWS * 32);
        u16* xbw = xbb + (p ^ 1) * (ROWS * 32);

        // issue x_{t+1} load early; latency hides under GEMM0
        float xv = 0.0f;
        if (t + 1 < T_STEPS && tid < ROWS * IN_DIM)
            xv = x[((size_t)(r0 + xrow) * T_STEPS + (t + 1)) * IN_DIM + xk];

        // ---- GEMM0: gates0 = [h0 | x_t] @ [w_hh0 | w_ih0]^T ----
        f32x4 acc[4] = {};
#pragma unroll
        for (int ks = 0; ks < 8; ++ks) {
            int ao = (ks * 64 + lkg * 16) ^ aswz;
            f16x8 a0 = *(const f16x8*)((const char*)h0p + lrow * 512 + ao);
#pragma unroll
            for (int g = 0; g < 4; ++g)
                acc[g] = __builtin_amdgcn_mfma_f32_16x16x32_f16(a0, w0[ks][g], acc[g], 0, 0, 0);
        }
        {
            int ao = (lkg * 16) ^ xswz;
            f16x8 a0 = *(const f16x8*)((const char*)xbp + lrow * 64 + ao);
#pragma unroll
            for (int g = 0; g < 4; ++g)
                acc[g] = __builtin_amdgcn_mfma_f32_16x16x32_f16(a0, w0[8][g], acc[g], 0, 0, 0);
        }

        // ---- epilogue 0: h0_new, c0; stage x_{t+1} ----
#pragma unroll
        for (int r = 0; r < 4; ++r) {
            float ig = acc[0][r] + bi0[0];
            float fg = acc[1][r] + bi0[1];
            float gg = acc[2][r] + bi0[2];
            float og = acc[3][r] + bi0[3];
            float c  = sigf(fg) * c0[r] + sigf(ig) * tanh_f(gg);
            c0[r] = c;
            float h  = sigf(og) * tanh_f(c);
            int row  = lkg * 4 + r;
            int byteo = row * 512 + (((wv * 16 + lrow) * 2) ^ ((row & 7) << 4));
            *(u16*)((char*)h0w + byteo) = __builtin_bit_cast(u16, (f16_t)h);
        }
        if (t + 1 < T_STEPS && tid < ROWS * IN_DIM) {
            int byteo = xrow * 64 + ((2 * xk) ^ ((xrow & 3) << 4));
            *(u16*)((char*)xbw + byteo) = __builtin_bit_cast(u16, (f16_t)xv);
        }

        BARRIER();   // BAR1: h0_new + x_{t+1} visible

        // ---- GEMM1: gates1 = h0_new @ w_ih1^T + h1 @ w_hh1^T ----
        f32x4 acc1[4] = {};
#pragma unroll
        for (int ks = 0; ks < 8; ++ks) {
            int ao = (ks * 64 + lkg * 16) ^ aswz;
            f16x8 a0 = *(const f16x8*)((const char*)h0w + lrow * 512 + ao);
#pragma unroll
            for (int g = 0; g < 4; ++g)
                acc1[g] = __builtin_amdgcn_mfma_f32_16x16x32_f16(a0, w1[ks][g], acc1[g], 0, 0, 0);
        }
#pragma unroll
        for (int ks = 0; ks < 8; ++ks) {
            int ao = (ks * 64 + lkg * 16) ^ aswz;
            f16x8 a0 = *(const f16x8*)((const char*)h1p + lrow * 512 + ao);
#pragma unroll
            for (int g = 0; g < 4; ++g)
                acc1[g] = __builtin_amdgcn_mfma_f32_16x16x32_f16(a0, w2[ks][g], acc1[g], 0, 0, 0);
        }

        // ---- epilogue 1: h1_new, c1 ----
#pragma unroll
        for (int r = 0; r < 4; ++r) {
            float ig = acc1[0][r] + bi1[0];
            float fg = acc1[1][r] + bi1[1];
            float gg = acc1[2][r] + bi1[2];
            float og = acc1[3][r] + bi1[3];
            float c  = sigf(fg) * c1[r] + sigf(ig) * tanh_f(gg);
            c1[r] = c;
            float h  = sigf(og) * tanh_f(c);
            int row  = lkg * 4 + r;
            int byteo = row * 512 + (((wv * 16 + lrow) * 2) ^ ((row & 7) << 4));
            *(u16*)((char*)h1w + byteo) = __builtin_bit_cast(u16, (f16_t)h);
        }

        BARRIER();   // BAR2: h1_new visible

        // ---- FC output: wave wv handles batch row wv ----
        {
            int byteo = wv * 512 + ((lane * 8) ^ ((wv & 7) << 4));
            uint2 raw = *(const uint2*)((const char*)h1w + byteo);
            float s = (float)__builtin_bit_cast(f16_t, (u16)(raw.x & 0xffff)) * fcw[0]
                    + (float)__builtin_bit_cast(f16_t, (u16)(raw.x >> 16))    * fcw[1]
                    + (float)__builtin_bit_cast(f16_t, (u16)(raw.y & 0xffff)) * fcw[2]
                    + (float)__builtin_bit_cast(f16_t, (u16)(raw.y >> 16))    * fcw[3];
#pragma unroll
            for (int off = 32; off > 0; off >>= 1) s += __shfl_xor(s, off);
            if (lane == 0) out[(size_t)(r0 + wv) * T_STEPS + t] = s + fcb;
        }
    }
}

extern "C" void kernel_launch(void* const* d_in, const int* in_sizes, int n_in,
                              void* d_out, int out_size, void* d_ws, size_t ws_size,
                              hipStream_t stream)
{
    const float* x    = (const float*)d_in[0];
    const float* wih0 = (const float*)d_in[1];
    const float* whh0 = (const float*)d_in[2];
    const float* bih0 = (const float*)d_in[3];
    const float* bhh0 = (const float*)d_in[4];
    const float* wih1 = (const float*)d_in[5];
    const float* whh1 = (const float*)d_in[6];
    const float* bih1 = (const float*)d_in[7];
    const float* bhh1 = (const float*)d_in[8];
    const float* fcw  = (const float*)d_in[9];
    const float* fcb  = (const float*)d_in[10];

    u16* wsw      = (u16*)d_ws;
    float* biases = (float*)((char*)d_ws + 1638400);

    prep_kernel<<<408, 256, 0, stream>>>(wih0, whh0, wih1, whh1,
                                         bih0, bhh0, bih1, bhh1, wsw, biases);
    lstm_fused<<<NBLK, 1024, 0, stream>>>(x, wsw, biases, fcw, fcb, (float*)d_out);
}

// Round 7
// 10296.548 us; speedup vs baseline: 1.8938x; 1.8938x over previous
//
#include <hip/hip_runtime.h>

typedef unsigned short u16;
typedef _Float16 f16_t;
typedef f16_t f16x8 __attribute__((ext_vector_type(8)));
typedef float f32x4 __attribute__((ext_vector_type(4)));

#define T_STEPS 256
#define IN_DIM  5
#define GRPS    64      // groups of 4 CUs
#define ROWS    64      // batch rows per group
#define NBLK    256

// d_ws byte layout:
//   WS_W    @ 0       : weight frags [16 slice][100 frag][64 lane][16B] = 1,638,400
//   WS_BIAS @ 1638400 : f32 bias0[1024], bias1[1024]
//   WS_GXH0 @ 1646592 : u16 [64 grp][64 row][256 col] = 2,097,152   (h0 exchange)
//   WS_GXH1 @ 3743744 : u16 [64 grp][64 row][256 col] = 2,097,152   (h1 exchange)
//   WS_CNT  @ 5840896 : u32 cnt0[64*16], cnt1[64*16]  (zeroed each launch by prep)
#define WS_BIAS 1638400
#define WS_GXH0 1646592
#define WS_GXH1 3743744
#define WS_CNT  5840896

__device__ __forceinline__ float sigf(float x)  { return 1.0f / (1.0f + __expf(-x)); }
__device__ __forceinline__ float tanh_f(float x){ return 1.0f - 2.0f / (__expf(2.0f * x) + 1.0f); }

__global__ void prep_kernel(const float* __restrict__ wih0, const float* __restrict__ whh0,
                            const float* __restrict__ wih1, const float* __restrict__ whh1,
                            const float* __restrict__ bih0, const float* __restrict__ bhh0,
                            const float* __restrict__ bih1, const float* __restrict__ bhh1,
                            u16* __restrict__ wsw, float* __restrict__ biases,
                            unsigned* __restrict__ cnt)
{
    int j = blockIdx.x * blockDim.x + threadIdx.x;
    if (j < 102400) {
        // j = (slice*100 + f)*64 + lane ; slice = sub*4 + wv
        int slice = j / 6400;
        int rem   = j - slice * 6400;
        int f     = rem >> 6;
        int lane  = rem & 63;
        int sub = slice >> 2, wv = slice & 3;
        int lrow = lane & 15;
        int kp = (lane >> 4) * 8;
        u16 tmp[8];
#pragma unroll
        for (int e = 0; e < 8; ++e) {
            int k = kp + e;
            float v;
            if (f < 36) {                              // GEMM0: gi*9 + ks (ks==8 -> w_ih0 pad)
                int gi = f / 9, ks = f - gi * 9;
                int grow = gi * 256 + sub * 64 + wv * 16 + lrow;
                v = (ks < 8) ? whh0[grow * 256 + ks * 32 + k]
                             : (k < IN_DIM ? wih0[grow * IN_DIM + k] : 0.0f);
            } else {                                   // GEMM1: 36 + gi*16 + ks (0-7 ih1, 8-15 hh1)
                int ff = f - 36;
                int gi = ff >> 4, ks = ff & 15;
                int grow = gi * 256 + sub * 64 + wv * 16 + lrow;
                v = (ks < 8) ? wih1[grow * 256 + ks * 32 + k]
                             : whh1[grow * 256 + (ks - 8) * 32 + k];
            }
            tmp[e] = __builtin_bit_cast(u16, (f16_t)v);
        }
        *(uint4*)(wsw + (size_t)j * 8) = *(uint4*)tmp;
    } else if (j < 103424) {
        int i = j - 102400;
        biases[i] = bih0[i] + bhh0[i];
    } else if (j < 104448) {
        int i = j - 103424;
        biases[1024 + i] = bih1[i] + bhh1[i];
    } else if (j < 106496) {
        cnt[j - 104448] = 0u;                          // monotone sync counters
    }
}

__global__ __launch_bounds__(256, 1) void lstm_fused(
    const float* __restrict__ x, const u16* __restrict__ wsw,
    const float* __restrict__ biases, const float* __restrict__ fcw_g,
    const float* __restrict__ fcb_g, float* __restrict__ out,
    u16* __restrict__ gxh0, u16* __restrict__ gxh1, unsigned* __restrict__ cnt)
{
    extern __shared__ char smem[];
    char* h0base = smem;               // [2][64 rows][512B] fp16, XOR-swizzled
    char* h1base = smem + 65536;       // [64][512B]  (single buffer, per-mt barrier)
    char* cstb   = smem + 98304;       // c-state: [2 layer][4 wv][4 mt][64 lane][16B]
    char* xbb    = smem + 131072;      // [64 rows][64B] x_t staged (zero-padded)

    const int tid  = threadIdx.x;
    const int wv   = tid >> 6;         // wave 0..3: owns hidden cols [sub*64+wv*16, +16), all 4 gates
    const int lane = tid & 63;
    const int lrow = lane & 15;
    const int lkg  = lane >> 4;
    const int sub  = blockIdx.x >> 6;  // CU index within group (0..3)
    const int grp  = blockIdx.x & 63;  // group; members {g, g+64, g+128, g+192}
    const int r0   = grp * ROWS;
    const int aswz = (lrow & 7) << 4;
    const int xswz = (lrow & 3) << 4;

    // ---- resident weight shard: 100 f16x8 frags = 400 regs/lane, AGPR-laundered.
    // Budget IS feasible now: 1 wave/SIMD (launch_bounds(256,1)) => 512 unified regs/wave.
    const u16* wbase = wsw + (size_t)(sub * 4 + wv) * 51200;
    f16x8 w0[4][9], w1g[4][16];
#pragma unroll
    for (int gi = 0; gi < 4; ++gi)
#pragma unroll
        for (int ks = 0; ks < 9; ++ks)
            w0[gi][ks] = *(const f16x8*)(wbase + (gi * 9 + ks) * 512 + lane * 8);
#pragma unroll
    for (int gi = 0; gi < 4; ++gi)
#pragma unroll
        for (int ks = 0; ks < 16; ++ks)
            w1g[gi][ks] = *(const f16x8*)(wbase + (36 + gi * 16 + ks) * 512 + lane * 8);
#pragma unroll
    for (int gi = 0; gi < 4; ++gi) {
#pragma unroll
        for (int ks = 0; ks < 9; ++ks)  asm volatile("" : "+a"(w0[gi][ks]));
#pragma unroll
        for (int ks = 0; ks < 16; ++ks) asm volatile("" : "+a"(w1g[gi][ks]));
    }

    float bi0[4], bi1[4];
#pragma unroll
    for (int gi = 0; gi < 4; ++gi) {
        int gcol = gi * 256 + sub * 64 + wv * 16 + lrow;
        bi0[gi] = biases[gcol];
        bi1[gi] = biases[1024 + gcol];
    }
    float fcw[4];
#pragma unroll
    for (int r = 0; r < 4; ++r) fcw[r] = fcw_g[lane * 4 + r];
    const float fcb = fcb_g[0];

    unsigned* c0p = cnt + grp * 16;
    unsigned* c1p = cnt + 1024 + grp * 16;
    u16* gx0 = gxh0 + grp * 16384;
    u16* gx1 = gxh1 + grp * 16384;

    // zero all LDS (h0 both bufs, h1, c-state, xb pads)
    for (int i = tid; i < 135168 / 4; i += 256) ((unsigned*)smem)[i] = 0u;
    __syncthreads();
    // stage x_0 (320 = 64 rows x 5)
    {
        int ra = tid / 5, ka = tid - ra * 5;
        float v = x[((size_t)(r0 + ra) * T_STEPS + 0) * IN_DIM + ka];
        *(u16*)(xbb + ra * 64 + ((2 * ka) ^ ((ra & 3) << 4))) = __builtin_bit_cast(u16, (f16_t)v);
        if (tid < 64) {
            int idx = tid + 256, rb = idx / 5, kb = idx - rb * 5;
            float v2 = x[((size_t)(r0 + rb) * T_STEPS + 0) * IN_DIM + kb];
            *(u16*)(xbb + rb * 64 + ((2 * kb) ^ ((rb & 3) << 4))) = __builtin_bit_cast(u16, (f16_t)v2);
        }
    }
    __syncthreads();

#pragma unroll 1
    for (int t = 0; t < T_STEPS; ++t) {
        const int p = t & 1;
        const char* h0p = h0base + p * 32768;
        char* h0w = h0base + (p ^ 1) * 32768;

        // prefetch x_{t+1}
        float xv0 = 0.0f, xv1 = 0.0f;
        if (t + 1 < T_STEPS) {
            int ra = tid / 5, ka = tid - ra * 5;
            xv0 = x[((size_t)(r0 + ra) * T_STEPS + (t + 1)) * IN_DIM + ka];
            if (tid < 64) {
                int idx = tid + 256, rb = idx / 5, kb = idx - rb * 5;
                xv1 = x[((size_t)(r0 + rb) * T_STEPS + (t + 1)) * IN_DIM + kb];
            }
        }

        // ---- GEMM0 + epilogue0, per 16-row mtile (h0 double-buffered: no races) ----
#pragma unroll
        for (int mt = 0; mt < 4; ++mt) {
            f32x4 acc[4] = {};
            const int arow = mt * 16 + lrow;
#pragma unroll
            for (int ks = 0; ks < 8; ++ks) {
                f16x8 a = *(const f16x8*)(h0p + arow * 512 + ((ks * 64 + lkg * 16) ^ aswz));
#pragma unroll
                for (int gi = 0; gi < 4; ++gi)
                    acc[gi] = __builtin_amdgcn_mfma_f32_16x16x32_f16(a, w0[gi][ks], acc[gi], 0, 0, 0);
            }
            {
                f16x8 a = *(const f16x8*)(xbb + arow * 64 + ((lkg * 16) ^ xswz));
#pragma unroll
                for (int gi = 0; gi < 4; ++gi)
                    acc[gi] = __builtin_amdgcn_mfma_f32_16x16x32_f16(a, w0[gi][8], acc[gi], 0, 0, 0);
            }
            // epilogue0: wave-local (owns all 4 gates of its cols)
            char* cp = cstb + ((wv * 4 + mt) * 64 + lane) * 16;
            f32x4 cold = *(f32x4*)cp, cnew;
#pragma unroll
            for (int r = 0; r < 4; ++r) {
                float ig = acc[0][r] + bi0[0];
                float fg = acc[1][r] + bi0[1];
                float gg = acc[2][r] + bi0[2];
                float og = acc[3][r] + bi0[3];
                float c  = sigf(fg) * cold[r] + sigf(ig) * tanh_f(gg);
                cnew[r] = c;
                u16 hb = __builtin_bit_cast(u16, (f16_t)(sigf(og) * tanh_f(c)));
                int row = mt * 16 + lkg * 4 + r;
                int col = sub * 64 + wv * 16 + lrow;
                *(u16*)(h0w + row * 512 + ((col * 2) ^ ((row & 7) << 4))) = hb;
                gx0[row * 256 + col] = hb;
            }
            *(f32x4*)cp = cnew;
        }

        // ---- group sync 1: h0 chunks visible (release/acquire, agent scope) ----
        if (tid == 0) {
            __hip_atomic_fetch_add(c0p, 1u, __ATOMIC_RELEASE, __HIP_MEMORY_SCOPE_AGENT);
            const unsigned tgt = 4u * (unsigned)(t + 1);
            while (__hip_atomic_load(c0p, __ATOMIC_ACQUIRE, __HIP_MEMORY_SCOPE_AGENT) < tgt)
                __builtin_amdgcn_s_sleep(4);
        }
        __syncthreads();

        // read other 3 CUs' h0 chunks -> LDS; stage x_{t+1}
        {
            int row = tid >> 2, q = tid & 3;
#pragma unroll
            for (int so = 1; so < 4; ++so) {
                int s2 = (sub + so) & 3;
                const u16* src = gx0 + row * 256 + s2 * 64 + q * 16;
                uint4 v0 = *(const uint4*)src;
                uint4 v1 = *(const uint4*)(src + 8);
                int cb = (s2 * 64 + q * 16) * 2;
                int sw = (row & 7) << 4;
                *(uint4*)(h0w + row * 512 + (cb ^ sw)) = v0;
                *(uint4*)(h0w + row * 512 + ((cb + 16) ^ sw)) = v1;
            }
            if (t + 1 < T_STEPS) {
                int ra = tid / 5, ka = tid - ra * 5;
                *(u16*)(xbb + ra * 64 + ((2 * ka) ^ ((ra & 3) << 4))) = __builtin_bit_cast(u16, (f16_t)xv0);
                if (tid < 64) {
                    int idx = tid + 256, rb = idx / 5, kb = idx - rb * 5;
                    *(u16*)(xbb + rb * 64 + ((2 * kb) ^ ((rb & 3) << 4))) = __builtin_bit_cast(u16, (f16_t)xv1);
                }
            }
        }
        __syncthreads();

        // ---- GEMM1 + epilogue1 per mtile; barrier between reads and in-place h1 writes ----
#pragma unroll
        for (int mt = 0; mt < 4; ++mt) {
            f32x4 acc[4] = {};
            const int arow = mt * 16 + lrow;
#pragma unroll
            for (int ks = 0; ks < 8; ++ks) {
                f16x8 a = *(const f16x8*)(h0w + arow * 512 + ((ks * 64 + lkg * 16) ^ aswz));
#pragma unroll
                for (int gi = 0; gi < 4; ++gi)
                    acc[gi] = __builtin_amdgcn_mfma_f32_16x16x32_f16(a, w1g[gi][ks], acc[gi], 0, 0, 0);
            }
#pragma unroll
            for (int ks = 8; ks < 16; ++ks) {
                f16x8 a = *(const f16x8*)(h1base + arow * 512 + (((ks - 8) * 64 + lkg * 16) ^ aswz));
#pragma unroll
                for (int gi = 0; gi < 4; ++gi)
                    acc[gi] = __builtin_amdgcn_mfma_f32_16x16x32_f16(a, w1g[gi][ks], acc[gi], 0, 0, 0);
            }
            __syncthreads();   // all waves done reading h1 rows of this mt before overwrite
            char* cp = cstb + 16384 + ((wv * 4 + mt) * 64 + lane) * 16;
            f32x4 cold = *(f32x4*)cp, cnew;
#pragma unroll
            for (int r = 0; r < 4; ++r) {
                float ig = acc[0][r] + bi1[0];
                float fg = acc[1][r] + bi1[1];
                float gg = acc[2][r] + bi1[2];
                float og = acc[3][r] + bi1[3];
                float c  = sigf(fg) * cold[r] + sigf(ig) * tanh_f(gg);
                cnew[r] = c;
                u16 hb = __builtin_bit_cast(u16, (f16_t)(sigf(og) * tanh_f(c)));
                int row = mt * 16 + lkg * 4 + r;
                int col = sub * 64 + wv * 16 + lrow;
                *(u16*)(h1base + row * 512 + ((col * 2) ^ ((row & 7) << 4))) = hb;
                gx1[row * 256 + col] = hb;
            }
            *(f32x4*)cp = cnew;
        }

        // ---- group sync 2: h1 chunks ----
        if (tid == 0) {
            __hip_atomic_fetch_add(c1p, 1u, __ATOMIC_RELEASE, __HIP_MEMORY_SCOPE_AGENT);
            const unsigned tgt = 4u * (unsigned)(t + 1);
            while (__hip_atomic_load(c1p, __ATOMIC_ACQUIRE, __HIP_MEMORY_SCOPE_AGENT) < tgt)
                __builtin_amdgcn_s_sleep(4);
        }
        __syncthreads();
        {
            int row = tid >> 2, q = tid & 3;
#pragma unroll
            for (int so = 1; so < 4; ++so) {
                int s2 = (sub + so) & 3;
                const u16* src = gx1 + row * 256 + s2 * 64 + q * 16;
                uint4 v0 = *(const uint4*)src;
                uint4 v1 = *(const uint4*)(src + 8);
                int cb = (s2 * 64 + q * 16) * 2;
                int sw = (row & 7) << 4;
                *(uint4*)(h1base + row * 512 + (cb ^ sw)) = v0;
                *(uint4*)(h1base + row * 512 + ((cb + 16) ^ sw)) = v1;
            }
        }
        __syncthreads();

        // ---- FC: this CU outputs rows [sub*16, sub*16+16) of the group ----
#pragma unroll
        for (int rr = 0; rr < 4; ++rr) {
            int row = sub * 16 + wv * 4 + rr;
            uint2 raw = *(const uint2*)(h1base + row * 512 + ((lane * 8) ^ ((row & 7) << 4)));
            float s = (float)__builtin_bit_cast(f16_t, (u16)(raw.x & 0xffff)) * fcw[0]
                    + (float)__builtin_bit_cast(f16_t, (u16)(raw.x >> 16))    * fcw[1]
                    + (float)__builtin_bit_cast(f16_t, (u16)(raw.y & 0xffff)) * fcw[2]
                    + (float)__builtin_bit_cast(f16_t, (u16)(raw.y >> 16))    * fcw[3];
#pragma unroll
            for (int off = 32; off > 0; off >>= 1) s += __shfl_xor(s, off);
            if (lane == 0) out[(size_t)(r0 + row) * T_STEPS + t] = s + fcb;
        }
    }
}

extern "C" void kernel_launch(void* const* d_in, const int* in_sizes, int n_in,
                              void* d_out, int out_size, void* d_ws, size_t ws_size,
                              hipStream_t stream)
{
    const float* x    = (const float*)d_in[0];
    const float* wih0 = (const float*)d_in[1];
    const float* whh0 = (const float*)d_in[2];
    const float* bih0 = (const float*)d_in[3];
    const float* bhh0 = (const float*)d_in[4];
    const float* wih1 = (const float*)d_in[5];
    const float* whh1 = (const float*)d_in[6];
    const float* bih1 = (const float*)d_in[7];
    const float* bhh1 = (const float*)d_in[8];
    const float* fcw  = (const float*)d_in[9];
    const float* fcb  = (const float*)d_in[10];

    u16* wsw      = (u16*)d_ws;
    float* biases = (float*)((char*)d_ws + WS_BIAS);
    u16* gxh0     = (u16*)((char*)d_ws + WS_GXH0);
    u16* gxh1     = (u16*)((char*)d_ws + WS_GXH1);
    unsigned* cnt = (unsigned*)((char*)d_ws + WS_CNT);

    prep_kernel<<<416, 256, 0, stream>>>(wih0, whh0, wih1, whh1,
                                         bih0, bhh0, bih1, bhh1, wsw, biases, cnt);
    lstm_fused<<<NBLK, 256, 135168, stream>>>(x, wsw, biases, fcw, fcb,
                                              (float*)d_out, gxh0, gxh1, cnt);
}